// Round 9
// baseline (901.946 us; speedup 1.0000x reference)
//
#include <hip/hip_runtime.h>
#include <math.h>

#define NN 16384      // nodes
#define E1N 65536     // edges level 1
#define NBATCH 256
#define NC2 65536     // clusters (level 2 and level 3)
#define KH 128        // edge-MLP hidden
#define OCS 136       // oc stride (f16)
#define MNSTR 548     // M node stride (f16) = 4*136+4; 548*4/... row groups 8 banks apart
#define ECAP 96       // edges per super-tile

typedef _Float16 f16;
typedef _Float16 f16x2 __attribute__((ext_vector_type(2)));
typedef _Float16 f16x4 __attribute__((ext_vector_type(4)));
typedef _Float16 f16x8 __attribute__((ext_vector_type(8)));
typedef float    f32x4 __attribute__((ext_vector_type(4)));

__device__ __forceinline__ float elu1(float x){ return x > 0.f ? x : expm1f(x); }

__device__ __forceinline__ float dot2acc(f16x2 a, f16x2 b, float c){
#if __has_builtin(__builtin_amdgcn_fdot2)
  return __builtin_amdgcn_fdot2(a, b, c, false);
#else
  return fmaf((float)a[0], (float)b[0], fmaf((float)a[1], (float)b[1], c));
#endif
}

// ---------------- generic counting + 3-phase scan ----------------
__global__ __launch_bounds__(256) void k_count(const int* __restrict__ arr, int* __restrict__ cnt, int n){
  int i = blockIdx.x*256 + threadIdx.x;
  if (i < n) atomicAdd(&cnt[arr[i]], 1);
}

__global__ __launch_bounds__(256) void k_scan1(const int* __restrict__ deg,
    int* __restrict__ ptr, int* __restrict__ partials){
  __shared__ int buf[256];
  int i = blockIdx.x*256 + threadIdx.x, t = threadIdx.x;
  int v = deg[i];
  buf[t] = v; __syncthreads();
  for (int o = 1; o < 256; o <<= 1){
    int x = (t >= o) ? buf[t-o] : 0;
    __syncthreads(); buf[t] += x; __syncthreads();
  }
  ptr[i] = buf[t] - v;
  if (t == 255) partials[blockIdx.x] = buf[255];
}

__global__ __launch_bounds__(256) void k_scan2(int* __restrict__ partials, int nb){
  __shared__ int buf[256];
  int t = threadIdx.x;
  int v = (t < nb) ? partials[t] : 0;
  buf[t] = v; __syncthreads();
  for (int o = 1; o < 256; o <<= 1){
    int x = (t >= o) ? buf[t-o] : 0;
    __syncthreads(); buf[t] += x; __syncthreads();
  }
  if (t < nb) partials[t] = buf[t] - v;
}

__global__ __launch_bounds__(256) void k_scan3(const int* __restrict__ partials,
    int* __restrict__ ptr, int* __restrict__ cur){
  int i = blockIdx.x*256 + threadIdx.x;
  int v = ptr[i] + partials[blockIdx.x];
  ptr[i] = v; cur[i] = v;
}

// ---------------- CSR fills ----------------
__global__ __launch_bounds__(256) void k_fill_edge(const int* __restrict__ ei, int* __restrict__ cursor,
    int* __restrict__ eids, int* __restrict__ srcs, int* __restrict__ dsts){
  int e = blockIdx.x*256 + threadIdx.x;
  if (e >= E1N) return;
  int s = ei[e];
  int p = atomicAdd(&cursor[s], 1);
  eids[p] = e; srcs[p] = s; dsts[p] = ei[E1N + e];
}

__global__ __launch_bounds__(256) void k_fill_dst(const int* __restrict__ eiL, int* __restrict__ cur,
    int* __restrict__ dsrc, int EL){
  int e = blockIdx.x*256 + threadIdx.x;
  if (e >= EL) return;
  int d = eiL[EL + e];
  int p = atomicAdd(&cur[d], 1);
  dsrc[p] = eiL[e];
}

__global__ __launch_bounds__(256) void k_fill_assign(const int* __restrict__ an, const int* __restrict__ ac,
    int* __restrict__ cur, int* __restrict__ an_sorted, int A){
  int a = blockIdx.x*256 + threadIdx.x;
  if (a >= A) return;
  int c = ac[a];
  int p = atomicAdd(&cur[c], 1);
  an_sorted[p] = an[a];
}

// ---------------- small converts ----------------
__global__ __launch_bounds__(256) void k_cvt16(const float* __restrict__ v, f16* __restrict__ o, int n){
  int t = blockIdx.x*256 + threadIdx.x;
  if (t < n) o[t] = (f16)v[t];
}

__global__ __launch_bounds__(256) void k_elu_both(float* __restrict__ v, f16* __restrict__ v16, int n){
  int t = blockIdx.x*256 + threadIdx.x;
  if (t < n){ float r = elu1(v[t]); v[t] = r; v16[t] = (f16)r; }
}

// ---------------- NNConv pieces ----------------
// pack [root | b2] into B-frag order, N = 2*MO cols
__global__ __launch_bounds__(256) void k_packPrep(const float* __restrict__ root,
    const float* __restrict__ b2, f16* __restrict__ Bp, int mi, int mo, int S, int NB){
  int t = blockIdx.x*256 + threadIdx.x;
  if (t >= NB*S*512) return;
  int j = t & 7, l = (t >> 3) & 63, cs = t >> 9;
  int s = cs % S, c = cs / S;
  int k_in = s*32 + ((l>>4)<<3) + j;
  int n = c*16 + (l & 15);
  float v = 0.f;
  if (k_in < mi) v = (n < mo) ? root[k_in*mo + n] : b2[k_in*mo + (n - mo)];
  Bp[t] = (f16)v;
}

// outb[n,o] = bias[o] + (x@root)[n,o]; bterm[n,o] = (x@b2)[n,o]   via MFMA
template<int MI, int S, int NB, int MO>
__global__ __launch_bounds__(256) void k_prep_mfma(const f16* __restrict__ A,
    const f16* __restrict__ Bp, const float* __restrict__ bias,
    float* __restrict__ outb, float* __restrict__ bterm){
  int l = threadIdx.x & 63, w = threadIdx.x >> 6;
  int r0 = blockIdx.x*64 + w*16;
  const f16* arow = A + (size_t)(r0 + (l & 15))*MI;
  f16x8 a[S];
  #pragma unroll
  for (int s=0;s<S;s++){
    int koff = s*32 + ((l>>4)<<3);
    if (koff < MI) a[s] = *(const f16x8*)(arow + koff);
    else           a[s] = (f16x8){0,0,0,0,0,0,0,0};
  }
  #pragma unroll
  for (int c=0;c<NB;c++){
    f32x4 acc = (f32x4){0.f,0.f,0.f,0.f};
    #pragma unroll
    for (int s=0;s<S;s++){
      f16x8 b = *(const f16x8*)(Bp + ((size_t)(c*S + s)*64 + l)*8);
      acc = __builtin_amdgcn_mfma_f32_16x16x32_f16(a[s], b, acc, 0, 0, 0);
    }
    int col = c*16 + (l & 15);
    #pragma unroll
    for (int r=0;r<4;r++){
      int row = r0 + ((l>>4)<<2) + r;
      if (col < MO) outb[(size_t)row*MO + col] = acc[r] + bias[col];
      else          bterm[(size_t)row*MO + (col - MO)] = acc[r];
    }
  }
}

// pack FULL W2 into B-frag order; q -> (oc=q>>3, kt=q&7), col k = kt*16 + (l&15)
__global__ __launch_bounds__(256) void k_w2pack_full(const float* __restrict__ W2,
    f16* __restrict__ Bp, int mi, int mo, int S){
  int t = blockIdx.x*256 + threadIdx.x;
  if (t >= mo*8*S*512) return;
  int j = t & 7, l = (t >> 3) & 63, cs = t >> 9;
  int s = cs % S, q = cs / S;
  int oc = q >> 3;
  int k  = (q & 7)*16 + (l & 15);
  int i  = s*32 + ((l>>4)<<3) + j;
  float v = (i < mi) ? W2[(size_t)k*mi*mo + (size_t)i*mo + oc] : 0.f;
  Bp[t] = (f16)v;
}

// FUSED NNConv v4: block = 16 CSR-consecutive nodes, 256 threads, oc-chunks of 4.
// LDS ~46.7 KB -> 3 blocks/CU. Super-tiles of <=96 edges: edge-MLP -> hb once;
// per 4-oc chunk: MFMA M[16n][4oc][128k] -> LDS; consume edges from LDS.
template<int MI, int S, int MO>
__global__ __launch_bounds__(256) void k_nnconv_fused4(const f16* __restrict__ xin16,
    const f16* __restrict__ W2p,
    const int* __restrict__ rowptr, const int* __restrict__ rowend,
    const int* __restrict__ srcs, const int* __restrict__ dsts,
    const int* __restrict__ eids,
    const float* __restrict__ ea, const float* __restrict__ W1,
    const float* __restrict__ b1,
    const float* __restrict__ bterm, float* __restrict__ outb){
  __shared__ __align__(16) f16   M[16*MNSTR];    // 17536 B
  __shared__ __align__(16) f16   hb[ECAP*OCS];   // 26112 B
  __shared__ __align__(16) float eas[ECAP*8];    //  3072 B
  int t = threadIdx.x, l = t & 63, w = t >> 6;
  int n0 = blockIdx.x*16;
  int estart = rowptr[n0], eend = rowend[n0+15];
  if (estart >= eend) return;                    // block-uniform
  const f16* arow = xin16 + (size_t)(n0 + (l&15))*MI;
  f16x8 a[S];
  #pragma unroll
  for (int s=0;s<S;s++){
    int koff = s*32 + ((l>>4)<<3);
    if (koff < MI) a[s] = *(const f16x8*)(arow + koff);
    else           a[s] = (f16x8){0,0,0,0,0,0,0,0};
  }
  const int NCHUNK = MO/4;
  int oc = t & 3, eslot = t >> 2;                // 64 edge slots x 4 oc
  for (int ebase = estart; ebase < eend; ebase += ECAP){
    int ecnt = eend - ebase; if (ecnt > ECAP) ecnt = ECAP;
    // ---- stage ea rows ----
    for (int idx = t; idx < ecnt*8; idx += 256){
      int e_ = idx >> 3, i = idx & 7;
      eas[idx] = (i < 7) ? ea[(size_t)eids[ebase + e_]*7 + i] : 0.f;
    }
    __syncthreads();
    // ---- fused edge-MLP -> hb ----
    for (int idx = t; idx < ecnt*32; idx += 256){
      int e_ = idx >> 5, p = idx & 31;
      int k0 = p*4;
      const float* xr = &eas[e_*8];
      float4 acc4 = *(const float4*)(b1 + k0);
      #pragma unroll
      for (int i=0;i<7;i++){
        float xv = xr[i];
        float4 wv = *(const float4*)(W1 + i*KH + k0);
        acc4.x = fmaf(xv, wv.x, acc4.x);
        acc4.y = fmaf(xv, wv.y, acc4.y);
        acc4.z = fmaf(xv, wv.z, acc4.z);
        acc4.w = fmaf(xv, wv.w, acc4.w);
      }
      f16x4 hv = { (f16)fmaxf(acc4.x,0.f), (f16)fmaxf(acc4.y,0.f),
                   (f16)fmaxf(acc4.z,0.f), (f16)fmaxf(acc4.w,0.f) };
      *(f16x4*)&hb[e_*OCS + k0] = hv;
    }
    __syncthreads();
    // ---- chunk loop (4 oc per chunk; wave w owns oc w) ----
    for (int c = 0; c < NCHUNK; c++){
      #pragma unroll
      for (int tt = 0; tt < 8; tt++){
        int q = (c*4 + w)*8 + tt;
        f32x4 acc = (f32x4){0.f,0.f,0.f,0.f};
        #pragma unroll
        for (int s=0;s<S;s++){
          f16x8 b = *(const f16x8*)(W2p + ((size_t)(q*S + s)*64 + l)*8);
          acc = __builtin_amdgcn_mfma_f32_16x16x32_f16(a[s], b, acc, 0, 0, 0);
        }
        int kpos = tt*16 + (l & 15);
        f16* mp = &M[w*OCS + kpos];
        #pragma unroll
        for (int r=0;r<4;r++)
          mp[(size_t)(((l>>4)<<2) + r)*MNSTR] = (f16)acc[r];
      }
      __syncthreads();
      // stage 2: consume edges (hb + M from LDS)
      #pragma unroll
      for (int r2 = 0; r2 < ECAP/48; r2++){   // 2 rounds of 64 slots
        int ee = r2*64 + eslot;
        if (ee < ecnt){
          int e = ebase + ee;
          int s_ = srcs[e];
          int ln = s_ - n0;
          float acc = bterm[(size_t)s_*MO + c*4 + oc];
          const f16* mrow = &M[(size_t)ln*MNSTR + oc*OCS];
          const f16* hrow = &hb[ee*OCS];
          #pragma unroll 4
          for (int kk=0; kk<16; kk++){
            f16x8 h8 = *(const f16x8*)(hrow + kk*8);
            f16x4 m0 = *(const f16x4*)(mrow + kk*8);
            f16x4 m1 = *(const f16x4*)(mrow + kk*8 + 4);
            acc = dot2acc((f16x2){h8[0],h8[1]}, (f16x2){m0[0],m0[1]}, acc);
            acc = dot2acc((f16x2){h8[2],h8[3]}, (f16x2){m0[2],m0[3]}, acc);
            acc = dot2acc((f16x2){h8[4],h8[5]}, (f16x2){m1[0],m1[1]}, acc);
            acc = dot2acc((f16x2){h8[6],h8[7]}, (f16x2){m1[2],m1[3]}, acc);
          }
          atomicAdd(&outb[(size_t)dsts[e]*MO + c*4 + oc], acc);
        }
      }
      __syncthreads();
    }
  }
}

// ---------------- pooling via cluster-CSR (f16 input) ----------------
__global__ __launch_bounds__(256) void k_pool_gather(const int* __restrict__ aptr,
    const int* __restrict__ aend, const int* __restrict__ an_sorted,
    const f16* __restrict__ h, const float* __restrict__ iso,
    f16* __restrict__ h16){
  int l = threadIdx.x & 63, w = threadIdx.x >> 6;
  int c = blockIdx.x*4 + w;
  int st = aptr[c], en = aend[c];
  float acc = 0.f;
  int e = st;
  for (; e+1 < en; e += 2){
    int n0 = an_sorted[e], n1 = an_sorted[e+1];
    acc += (float)h[(size_t)n0*64 + l];
    acc += (float)h[(size_t)n1*64 + l];
  }
  if (e < en) acc += (float)h[(size_t)an_sorted[e]*64 + l];
  int cnt = en - st;
  float val = (cnt > 0) ? acc / (float)cnt : 0.f;
  h16[(size_t)c*128 + l] = (f16)val;
  h16[(size_t)c*128 + 64 + l] = (f16)iso[(size_t)c*64 + l];
}

// ---------------- GraphConv ----------------
__global__ __launch_bounds__(256) void k_packB_gc(const float* __restrict__ Wrel,
    const float* __restrict__ Wroot, f16* __restrict__ Bp, int S){
  int t = blockIdx.x*256 + threadIdx.x;
  if (t >= 8*S*512) return;
  int j = t & 7, l = (t >> 3) & 63, cs = t >> 9;
  int s = cs % S, c = cs / S;
  int k = s*32 + ((l>>4)<<3) + j;
  int n = (c<<4) + (l & 15);
  float v = (n < 64) ? Wrel[k*64 + n] : Wroot[k*64 + (n - 64)];
  Bp[t] = (f16)v;
}

// [65536 x K] @ [K x 128] -> y16 (rel, cols 0:64), rbuf16 (root+bias, cols 64:128)
template<int S>
__global__ __launch_bounds__(256) void k_gc_mfma(const f16* __restrict__ A,
    const f16* __restrict__ Bp, const float* __restrict__ bias,
    f16* __restrict__ y16, f16* __restrict__ rbuf16){
  int l = threadIdx.x & 63, w = threadIdx.x >> 6;
  int r0 = blockIdx.x*64 + w*16;
  const f16* arow = A + (size_t)(r0 + (l & 15))*(S*32);
  f16x8 a[S];
  #pragma unroll
  for (int s=0;s<S;s++) a[s] = *(const f16x8*)(arow + s*32 + ((l>>4)<<3));
  f32x4 acc[8];
  #pragma unroll
  for (int c=0;c<8;c++) acc[c] = (f32x4){0.f,0.f,0.f,0.f};
  #pragma unroll
  for (int c=0;c<8;c++){
    #pragma unroll
    for (int s=0;s<S;s++){
      f16x8 b = *(const f16x8*)(Bp + ((size_t)(c*S + s)*64 + l)*8);
      acc[c] = __builtin_amdgcn_mfma_f32_16x16x32_f16(a[s], b, acc[c], 0, 0, 0);
    }
  }
  #pragma unroll
  for (int c=0;c<8;c++){
    int col = c*16 + (l & 15);
    #pragma unroll
    for (int r=0;r<4;r++){
      int row = r0 + ((l>>4)<<2) + r;
      if (col < 64) y16[(size_t)row*64 + col] = (f16)acc[c][r];
      else          rbuf16[(size_t)row*64 + (col-64)] = (f16)(acc[c][r] + bias[col-64]);
    }
  }
}

// dst-CSR gather (f16 in/out): out[n] = elu(rbuf[n] + sum y[dsrc[e]])
__global__ __launch_bounds__(256) void k_gc_gather(const int* __restrict__ dptr,
    const int* __restrict__ dend, const int* __restrict__ dsrc,
    const f16* __restrict__ y16, const f16* __restrict__ rbuf16,
    f16* __restrict__ o16){
  int l = threadIdx.x & 63, w = threadIdx.x >> 6;
  int n = blockIdx.x*4 + w;
  int st = dptr[n], en = dend[n];
  float acc = (float)rbuf16[(size_t)n*64 + l];
  int e = st;
  for (; e+1 < en; e += 2){
    int s0 = dsrc[e], s1 = dsrc[e+1];
    acc += (float)y16[(size_t)s0*64 + l];
    acc += (float)y16[(size_t)s1*64 + l];
  }
  if (e < en) acc += (float)y16[(size_t)dsrc[e]*64 + l];
  o16[(size_t)n*64 + l] = (f16)elu1(acc);
}

// ---------------- sorted-segment batch sum ----------------
__device__ __forceinline__ int lowerb(const int* __restrict__ a, int n, int key){
  int lo = 0, hi = n;
  while (lo < hi){ int m = (lo + hi) >> 1; if (a[m] < key) lo = m + 1; else hi = m; }
  return lo;
}

template<bool F16IN>
__global__ __launch_bounds__(256) void k_batchsum_seg(const int* __restrict__ batch,
    const float* __restrict__ h32, const f16* __restrict__ h16,
    float* __restrict__ x123, int n_nodes, int off){
  __shared__ float red[4][64];
  int b = blockIdx.x;
  int lo = lowerb(batch, n_nodes, b);
  int hi = lowerb(batch, n_nodes, b+1);
  int col = threadIdx.x & 63, wq = threadIdx.x >> 6;
  float acc = 0.f;
  for (int n = lo + wq; n < hi; n += 4)
    acc += F16IN ? (float)h16[(size_t)n*64 + col] : h32[(size_t)n*64 + col];
  red[wq][col] = acc;
  __syncthreads();
  if (threadIdx.x < 64){
    float s = red[0][threadIdx.x] + red[1][threadIdx.x] + red[2][threadIdx.x] + red[3][threadIdx.x];
    x123[b*192 + off + threadIdx.x] = s;
  }
}

// ---------------- FC head ----------------
__global__ __launch_bounds__(256) void k_fc1(const float* __restrict__ x123,
    const float* __restrict__ W, const float* __restrict__ b, float* __restrict__ t1){
  int t = blockIdx.x*256 + threadIdx.x;
  if (t >= NBATCH*64) return;
  int bb = t >> 6, o = t & 63;
  const float* xr = x123 + bb*192;
  float acc = b[o];
  for (int j=0;j<192;j++) acc = fmaf(xr[j], W[j*64+o] + W[(192+j)*64+o], acc);
  t1[t] = elu1(acc);
}

__global__ __launch_bounds__(256) void k_fc2(const float* __restrict__ t1,
    const float* __restrict__ W, const float* __restrict__ b, float* __restrict__ t2){
  int t = blockIdx.x*256 + threadIdx.x;
  if (t >= NBATCH*32) return;
  int bb = t >> 5, o = t & 31;
  float acc = b[o];
  for (int j=0;j<64;j++) acc = fmaf(t1[bb*64+j], W[j*32+o], acc);
  t2[t] = elu1(acc);
}

__global__ __launch_bounds__(256) void k_fc3(const float* __restrict__ t2,
    const float* __restrict__ W, const float* __restrict__ b, float* __restrict__ out){
  int t = blockIdx.x*256 + threadIdx.x;
  if (t >= NBATCH) return;
  float acc = b[0];
  for (int j=0;j<32;j++) acc = fmaf(t2[t*32+j], W[j], acc);
  out[t] = acc;
}

static inline int cdiv(long long a, int b){ return (int)((a + b - 1) / b); }

extern "C" void kernel_launch(void* const* d_in, const int* in_sizes, int n_in,
                              void* d_out, int out_size, void* d_ws, size_t ws_size,
                              hipStream_t stream) {
  const float* x0    = (const float*)d_in[0];
  const int*   ei    = (const int*)d_in[1];
  const float* ea    = (const float*)d_in[2];
  const int*   batch = (const int*)d_in[3];
  const int*   a2n   = (const int*)d_in[4];
  const int*   a2c   = (const int*)d_in[5];
  const float* iso2  = (const float*)d_in[6];
  const int*   ei2   = (const int*)d_in[7];
  const int*   b2arr = (const int*)d_in[8];
  const int*   a3n   = (const int*)d_in[9];
  const int*   a3c   = (const int*)d_in[10];
  const float* iso3  = (const float*)d_in[11];
  const int*   ei3   = (const int*)d_in[12];
  const int*   b3arr = (const int*)d_in[13];
  const float* nnp[3][6];
  for (int c=0;c<3;c++) for (int p=0;p<6;p++) nnp[c][p] = (const float*)d_in[14 + 6*c + p];
  const float* c4W[3]; const float* c5W[3]; const float* c6W[3]; const float* c7W[3];
  for (int p=0;p<3;p++){ c4W[p]=(const float*)d_in[32+p]; c5W[p]=(const float*)d_in[35+p];
                         c6W[p]=(const float*)d_in[38+p]; c7W[p]=(const float*)d_in[41+p]; }
  const float* fc1W=(const float*)d_in[44]; const float* fc1b=(const float*)d_in[45];
  const float* fc2W=(const float*)d_in[46]; const float* fc2b=(const float*)d_in[47];
  const float* fc3W=(const float*)d_in[48]; const float* fc3b=(const float*)d_in[49];
  float* outp = (float*)d_out;

  // ---- workspace carve ----
  char* ws = (char*)d_ws; size_t off = 0;
  auto alloc = [&](size_t bytes)->void*{ void* p = ws + off; off += (bytes + 255) & ~(size_t)255; return p; };
  const size_t SZ_R0 = (size_t)92*1024*1024;
  char* r0 = (char*)alloc(SZ_R0);
  // phase-1 view (NNConv): W2p 1MB | prepB 16KB | bterm 4MB
  f16*   W2p   = (f16*)r0;
  f16*   prepB = (f16*)(r0 + 2*1024*1024);
  float* bterm = (float*)(r0 + 2*1024*1024 + 64*1024);
  // phase-2 view (levels; written only after NNConvs complete)
  size_t o2 = 0;
  auto a2 = [&](size_t bytes)->char*{ char* p = r0 + o2; o2 += (bytes + 255) & ~(size_t)255; return p; };
  f16*   h16   = (f16*)  a2((size_t)NC2*128*2);   // 16 MB
  f16*   y16   = (f16*)  a2((size_t)NC2*64*2);    //  8 MB
  f16*   rbuf16= (f16*)  a2((size_t)NC2*64*2);    //  8 MB
  f16*   gB16  = (f16*)  a2((size_t)NC2*64*2);    //  8 MB
  f16*   g16   = (f16*)  a2((size_t)NC2*64*2);    //  8 MB
  f16*   BpGc  = (f16*)  a2((size_t)8*4*512*2);   // 32 KB
  int*   aptr  = (int*)  a2((size_t)NC2*4);
  int*   acur  = (int*)  a2((size_t)NC2*4);
  int*   dptr  = (int*)  a2((size_t)NC2*4);
  int*   dcur  = (int*)  a2((size_t)NC2*4);
  int*   ldeg  = (int*)  a2((size_t)NC2*4);
  int*   ans   = (int*)  a2((size_t)196608*4);
  int*   dsrc  = (int*)  a2((size_t)262144*4);
  // persistent
  float* hA    = (float*)alloc((size_t)NN*32*4);
  float* hB    = (float*)alloc((size_t)NN*64*4);
  float* hC    = (float*)alloc((size_t)NN*64*4);
  f16*   x016  = (f16*)  alloc((size_t)NN*16*2);
  f16*   hA16  = (f16*)  alloc((size_t)NN*32*2);
  f16*   hB16  = (f16*)  alloc((size_t)NN*64*2);
  f16*   hC16  = (f16*)  alloc((size_t)NN*64*2);
  int*   deg   = (int*)  alloc((size_t)NN*4);
  int*   cursor= (int*)  alloc((size_t)NN*4);
  int*   rowptr= (int*)  alloc((size_t)NN*4);
  int*   eids  = (int*)  alloc((size_t)E1N*4);
  int*   srcs  = (int*)  alloc((size_t)E1N*4);
  int*   dsts  = (int*)  alloc((size_t)E1N*4);
  int*   parts = (int*)  alloc((size_t)256*4);
  float* x123  = (float*)alloc((size_t)NBATCH*192*4);
  float* t1    = (float*)alloc((size_t)NBATCH*64*4);
  float* t2    = (float*)alloc((size_t)NBATCH*32*4);
  (void)ws_size; (void)n_in; (void)in_sizes; (void)out_size;

  auto scan = [&](const int* dg, int n, int* ptr, int* cur){
    k_scan1<<<n/256,256,0,stream>>>(dg, ptr, parts);
    k_scan2<<<1,256,0,stream>>>(parts, n/256);
    k_scan3<<<n/256,256,0,stream>>>(parts, ptr, cur);
  };

  // ---- edge CSR by src (once; reused by all 3 convs) ----
  hipMemsetAsync(deg, 0, (size_t)NN*4, stream);
  k_count<<<cdiv(E1N,256),256,0,stream>>>(ei, deg, E1N);
  scan(deg, NN, rowptr, cursor);
  k_fill_edge<<<cdiv(E1N,256),256,0,stream>>>(ei, cursor, eids, srcs, dsts);
  k_cvt16<<<cdiv((long long)NN*16,256),256,0,stream>>>(x0, x016, NN*16);

  // ---- NNConv x3 (fused v4) ----
  auto run_nnconv = [&](const f16* xin16, int mi, int mo,
                        const float* const* P, float* outb, f16* out16){
    const float* W1=P[0]; const float* b1=P[1]; const float* W2=P[2];
    const float* b2=P[3]; const float* root=P[4]; const float* bias=P[5];
    const int S = (mi > 32) ? 2 : 1;
    const int NB = (2*mo)/16;
    k_packPrep<<<cdiv((long long)NB*S*512,256),256,0,stream>>>(root, b2, prepB, mi, mo, S, NB);
    if (mi==16)      k_prep_mfma<16,1,4,32><<<NN/64,256,0,stream>>>(xin16, prepB, bias, outb, bterm);
    else if (mi==32) k_prep_mfma<32,1,8,64><<<NN/64,256,0,stream>>>(xin16, prepB, bias, outb, bterm);
    else             k_prep_mfma<64,2,8,64><<<NN/64,256,0,stream>>>(xin16, prepB, bias, outb, bterm);
    k_w2pack_full<<<cdiv((long long)mo*8*S*512,256),256,0,stream>>>(W2, W2p, mi, mo, S);
    if (mi==16)      k_nnconv_fused4<16,1,32><<<NN/16,256,0,stream>>>(xin16, W2p, rowptr, cursor, srcs, dsts, eids, ea, W1, b1, bterm, outb);
    else if (mi==32) k_nnconv_fused4<32,1,64><<<NN/16,256,0,stream>>>(xin16, W2p, rowptr, cursor, srcs, dsts, eids, ea, W1, b1, bterm, outb);
    else             k_nnconv_fused4<64,2,64><<<NN/16,256,0,stream>>>(xin16, W2p, rowptr, cursor, srcs, dsts, eids, ea, W1, b1, bterm, outb);
    k_elu_both<<<cdiv((long long)NN*mo,256),256,0,stream>>>(outb, out16, NN*mo);
  };
  run_nnconv(x016, 16, 32, nnp[0], hA, hA16);
  run_nnconv(hA16, 32, 64, nnp[1], hB, hB16);
  run_nnconv(hB16, 64, 64, nnp[2], hC, hC16);

  // level-1 batch sum (fp32 input)
  k_batchsum_seg<false><<<NBATCH,256,0,stream>>>(batch, hC, nullptr, x123, NN, 0);

  // ---- levels 2 and 3 (f16 end-to-end, fp32 accumulate) ----
  auto run_level = [&](const int* an, const int* ac, int A, const float* iso,
                       const int* eiL, int EL, const int* batchL,
                       const float* const* cA, const float* const* cB, int off123){
    hipMemsetAsync(ldeg, 0, (size_t)NC2*4, stream);
    k_count<<<cdiv(A,256),256,0,stream>>>(ac, ldeg, A);
    scan(ldeg, NC2, aptr, acur);
    k_fill_assign<<<cdiv(A,256),256,0,stream>>>(an, ac, acur, ans, A);
    hipMemsetAsync(ldeg, 0, (size_t)NC2*4, stream);
    k_count<<<cdiv(EL,256),256,0,stream>>>(eiL + EL, ldeg, EL);
    scan(ldeg, NC2, dptr, dcur);
    k_fill_dst<<<cdiv(EL,256),256,0,stream>>>(eiL, dcur, dsrc, EL);
    k_pool_gather<<<NC2/4,256,0,stream>>>(aptr, acur, ans, hC16, iso, h16);
    k_packB_gc<<<cdiv((long long)8*4*512,256),256,0,stream>>>(cA[0], cA[1], BpGc, 4);
    k_gc_mfma<4><<<NC2/64,256,0,stream>>>(h16, BpGc, cA[2], y16, rbuf16);
    k_gc_gather<<<NC2/4,256,0,stream>>>(dptr, dcur, dsrc, y16, rbuf16, g16);
    k_packB_gc<<<cdiv((long long)8*2*512,256),256,0,stream>>>(cB[0], cB[1], BpGc, 2);
    k_gc_mfma<2><<<NC2/64,256,0,stream>>>(g16, BpGc, cB[2], y16, rbuf16);
    k_gc_gather<<<NC2/4,256,0,stream>>>(dptr, dcur, dsrc, y16, rbuf16, gB16);
    k_batchsum_seg<true><<<NBATCH,256,0,stream>>>(batchL, nullptr, gB16, x123, NC2, off123);
  };
  run_level(a2n, a2c, 131072, iso2, ei2, 262144, b2arr, c4W, c5W, 64);
  run_level(a3n, a3c, 196608, iso3, ei3, 262144, b3arr, c6W, c7W, 128);

  // ---- FC head ----
  k_fc1<<<cdiv((long long)NBATCH*64,256),256,0,stream>>>(x123, fc1W, fc1b, t1);
  k_fc2<<<cdiv((long long)NBATCH*32,256),256,0,stream>>>(t1, fc2W, fc2b, t2);
  k_fc3<<<cdiv(NBATCH,256),256,0,stream>>>(t2, fc3W, fc3b, outp);
}

// Round 10
// 747.211 us; speedup vs baseline: 1.2071x; 1.2071x over previous
//
#include <hip/hip_runtime.h>
#include <math.h>

#define NN 16384      // nodes
#define E1N 65536     // edges level 1
#define NBATCH 256
#define NC2 65536     // clusters (level 2 and level 3)
#define A2N 131072
#define A3N 196608
#define ELV 262144    // edges per level graph
#define KH 128        // edge-MLP hidden
#define OCS 136       // oc stride (f16)
#define MNSTR 1092    // M node stride (f16) — R8-verified low-conflict
#define ECAP 96       // edges per super-tile

typedef _Float16 f16;
typedef _Float16 f16x2 __attribute__((ext_vector_type(2)));
typedef _Float16 f16x4 __attribute__((ext_vector_type(4)));
typedef _Float16 f16x8 __attribute__((ext_vector_type(8)));
typedef float    f32x4 __attribute__((ext_vector_type(4)));

__device__ __forceinline__ float elu1(float x){ return x > 0.f ? x : expm1f(x); }

__device__ __forceinline__ float dot2acc(f16x2 a, f16x2 b, float c){
#if __has_builtin(__builtin_amdgcn_fdot2)
  return __builtin_amdgcn_fdot2(a, b, c, false);
#else
  return fmaf((float)a[0], (float)b[0], fmaf((float)a[1], (float)b[1], c));
#endif
}

// ---------------- segmented 3-phase scan ----------------
__global__ __launch_bounds__(256) void k_scan1(const int* __restrict__ deg,
    int* __restrict__ ptr, int* __restrict__ partials){
  __shared__ int buf[256];
  int i = blockIdx.x*256 + threadIdx.x, t = threadIdx.x;
  int v = deg[i];
  buf[t] = v; __syncthreads();
  for (int o = 1; o < 256; o <<= 1){
    int x = (t >= o) ? buf[t-o] : 0;
    __syncthreads(); buf[t] += x; __syncthreads();
  }
  ptr[i] = buf[t] - v;
  if (t == 255) partials[blockIdx.x] = buf[255];
}

// per-segment exclusive scan of partials; block b handles partials[b*nb .. b*nb+nb)
__global__ __launch_bounds__(256) void k_scan2seg(int* __restrict__ partials, int nb){
  __shared__ int buf[256];
  int t = threadIdx.x, base = blockIdx.x*nb;
  int v = (t < nb) ? partials[base + t] : 0;
  buf[t] = v; __syncthreads();
  for (int o = 1; o < 256; o <<= 1){
    int x = (t >= o) ? buf[t-o] : 0;
    __syncthreads(); buf[t] += x; __syncthreads();
  }
  if (t < nb) partials[base + t] = buf[t] - v;
}

__global__ __launch_bounds__(256) void k_scan3(const int* __restrict__ partials,
    int* __restrict__ ptr, int* __restrict__ cur){
  int i = blockIdx.x*256 + threadIdx.x;
  int v = ptr[i] + partials[blockIdx.x];
  ptr[i] = v; cur[i] = v;
}

// ---------------- level-1 CSR (src + dst in one pass) ----------------
__global__ __launch_bounds__(256) void k_count_edge_dual(const int* __restrict__ ei, int* __restrict__ deg){
  int e = blockIdx.x*256 + threadIdx.x;
  if (e >= E1N) return;
  atomicAdd(&deg[ei[e]], 1);
  atomicAdd(&deg[NN + ei[E1N + e]], 1);
}

__global__ __launch_bounds__(256) void k_fill_edge_dual(const int* __restrict__ ei, int* __restrict__ cur,
    int* __restrict__ eids, int* __restrict__ srcs, int* __restrict__ dpos){
  int e = blockIdx.x*256 + threadIdx.x;
  if (e >= E1N) return;
  int s = ei[e], d = ei[E1N + e];
  int p = atomicAdd(&cur[s], 1);
  eids[p] = e; srcs[p] = s;
  int p2 = atomicAdd(&cur[NN + d], 1);
  dpos[p2] = p;
}

// ---------------- level-2/3 CSR (dual) ----------------
__global__ __launch_bounds__(256) void k_count_assign_dual(const int* __restrict__ a2c,
    const int* __restrict__ a3c, int* __restrict__ ldegA){
  int i = blockIdx.x*256 + threadIdx.x;
  if (i < A2N) atomicAdd(&ldegA[a2c[i]], 1);
  else if (i < A2N + A3N) atomicAdd(&ldegA[NC2 + a3c[i - A2N]], 1);
}

__global__ __launch_bounds__(256) void k_fill_assign_dual(const int* __restrict__ a2n,
    const int* __restrict__ a2c, const int* __restrict__ a3n, const int* __restrict__ a3c,
    int* __restrict__ curA, int* __restrict__ ans2, int* __restrict__ ans3){
  int i = blockIdx.x*256 + threadIdx.x;
  if (i < A2N){
    int p = atomicAdd(&curA[a2c[i]], 1); ans2[p] = a2n[i];
  } else if (i < A2N + A3N){
    int j = i - A2N;
    int p = atomicAdd(&curA[NC2 + a3c[j]], 1); ans3[p] = a3n[j];
  }
}

__global__ __launch_bounds__(256) void k_count_dst_dual(const int* __restrict__ ei2,
    const int* __restrict__ ei3, int* __restrict__ ldegD){
  int i = blockIdx.x*256 + threadIdx.x;
  if (i < ELV) atomicAdd(&ldegD[ei2[ELV + i]], 1);
  else if (i < 2*ELV) atomicAdd(&ldegD[NC2 + ei3[ELV + (i - ELV)]], 1);
}

__global__ __launch_bounds__(256) void k_fill_dst_dual(const int* __restrict__ ei2,
    const int* __restrict__ ei3, int* __restrict__ curD,
    int* __restrict__ dsrc2, int* __restrict__ dsrc3){
  int i = blockIdx.x*256 + threadIdx.x;
  if (i < ELV){
    int p = atomicAdd(&curD[ei2[ELV + i]], 1); dsrc2[p] = ei2[i];
  } else if (i < 2*ELV){
    int j = i - ELV;
    int p = atomicAdd(&curD[NC2 + ei3[ELV + j]], 1); dsrc3[p] = ei3[j];
  }
}

// ---------------- small converts ----------------
__global__ __launch_bounds__(256) void k_cvt16(const float* __restrict__ v, f16* __restrict__ o, int n){
  int t = blockIdx.x*256 + threadIdx.x;
  if (t < n) o[t] = (f16)v[t];
}

// ---------------- NNConv pieces ----------------
__global__ __launch_bounds__(256) void k_packPrep(const float* __restrict__ root,
    const float* __restrict__ b2, f16* __restrict__ Bp, int mi, int mo, int S, int NB){
  int t = blockIdx.x*256 + threadIdx.x;
  if (t >= NB*S*512) return;
  int j = t & 7, l = (t >> 3) & 63, cs = t >> 9;
  int s = cs % S, c = cs / S;
  int k_in = s*32 + ((l>>4)<<3) + j;
  int n = c*16 + (l & 15);
  float v = 0.f;
  if (k_in < mi) v = (n < mo) ? root[k_in*mo + n] : b2[k_in*mo + (n - mo)];
  Bp[t] = (f16)v;
}

// prep[n,o] = bias[o] + (x@root)[n,o]; bterm[n,o] = (x@b2)[n,o]
template<int MI, int S, int NB, int MO>
__global__ __launch_bounds__(256) void k_prep_mfma(const f16* __restrict__ A,
    const f16* __restrict__ Bp, const float* __restrict__ bias,
    float* __restrict__ prep, float* __restrict__ bterm){
  int l = threadIdx.x & 63, w = threadIdx.x >> 6;
  int r0 = blockIdx.x*64 + w*16;
  const f16* arow = A + (size_t)(r0 + (l & 15))*MI;
  f16x8 a[S];
  #pragma unroll
  for (int s=0;s<S;s++){
    int koff = s*32 + ((l>>4)<<3);
    if (koff < MI) a[s] = *(const f16x8*)(arow + koff);
    else           a[s] = (f16x8){0,0,0,0,0,0,0,0};
  }
  #pragma unroll
  for (int c=0;c<NB;c++){
    f32x4 acc = (f32x4){0.f,0.f,0.f,0.f};
    #pragma unroll
    for (int s=0;s<S;s++){
      f16x8 b = *(const f16x8*)(Bp + ((size_t)(c*S + s)*64 + l)*8);
      acc = __builtin_amdgcn_mfma_f32_16x16x32_f16(a[s], b, acc, 0, 0, 0);
    }
    int col = c*16 + (l & 15);
    #pragma unroll
    for (int r=0;r<4;r++){
      int row = r0 + ((l>>4)<<2) + r;
      if (col < MO) prep[(size_t)row*MO + col] = acc[r] + bias[col];
      else          bterm[(size_t)row*MO + (col - MO)] = acc[r];
    }
  }
}

__global__ __launch_bounds__(256) void k_w2pack_full(const float* __restrict__ W2,
    f16* __restrict__ Bp, int mi, int mo, int S){
  int t = blockIdx.x*256 + threadIdx.x;
  if (t >= mo*8*S*512) return;
  int j = t & 7, l = (t >> 3) & 63, cs = t >> 9;
  int s = cs % S, q = cs / S;
  int oc = q >> 3;
  int k  = (q & 7)*16 + (l & 15);
  int i  = s*32 + ((l>>4)<<3) + j;
  float v = (i < mi) ? W2[(size_t)k*mi*mo + (size_t)i*mo + oc] : 0.f;
  Bp[t] = (f16)v;
}

// FUSED NNConv v5: R8 geometry (16 nodes/block, 8-oc chunks, MNSTR 1092) +
// bterm staged to LDS + msg written to coalesced f16 buffer (no atomics).
template<int MI, int S, int MO>
__global__ __launch_bounds__(256) void k_nnconv_fused5(const f16* __restrict__ xin16,
    const f16* __restrict__ W2p,
    const int* __restrict__ rowptr, const int* __restrict__ rowend,
    const int* __restrict__ srcs, const int* __restrict__ eids,
    const float* __restrict__ ea, const float* __restrict__ W1,
    const float* __restrict__ b1,
    const float* __restrict__ bterm, f16* __restrict__ msg16){
  __shared__ __align__(16) f16   M[16*MNSTR];    // 34944 B
  __shared__ __align__(16) f16   hb[ECAP*OCS];   // 26112 B
  __shared__ __align__(16) float eas[ECAP*8];    //  3072 B
  __shared__ float bt[16*MO];                    // 4096/2048 B
  int t = threadIdx.x, l = t & 63, w = t >> 6;
  int n0 = blockIdx.x*16;
  int estart = rowptr[n0], eend = rowend[n0+15];
  if (estart >= eend) return;                    // block-uniform
  // bterm tile -> LDS (coalesced)
  for (int idx = t; idx < 16*MO; idx += 256) bt[idx] = bterm[(size_t)n0*MO + idx];
  const f16* arow = xin16 + (size_t)(n0 + (l&15))*MI;
  f16x8 a[S];
  #pragma unroll
  for (int s=0;s<S;s++){
    int koff = s*32 + ((l>>4)<<3);
    if (koff < MI) a[s] = *(const f16x8*)(arow + koff);
    else           a[s] = (f16x8){0,0,0,0,0,0,0,0};
  }
  const int NCHUNK = MO/8;
  int oc = t & 7, eslot = t >> 3;                // 32 edge slots
  for (int ebase = estart; ebase < eend; ebase += ECAP){
    int ecnt = eend - ebase; if (ecnt > ECAP) ecnt = ECAP;
    // ---- stage ea rows ----
    for (int idx = t; idx < ecnt*8; idx += 256){
      int e_ = idx >> 3, i = idx & 7;
      eas[idx] = (i < 7) ? ea[(size_t)eids[ebase + e_]*7 + i] : 0.f;
    }
    __syncthreads();
    // ---- fused edge-MLP -> hb ----
    for (int idx = t; idx < ecnt*32; idx += 256){
      int e_ = idx >> 5, p = idx & 31;
      int k0 = p*4;
      const float* xr = &eas[e_*8];
      float4 acc4 = *(const float4*)(b1 + k0);
      #pragma unroll
      for (int i=0;i<7;i++){
        float xv = xr[i];
        float4 wv = *(const float4*)(W1 + i*KH + k0);
        acc4.x = fmaf(xv, wv.x, acc4.x);
        acc4.y = fmaf(xv, wv.y, acc4.y);
        acc4.z = fmaf(xv, wv.z, acc4.z);
        acc4.w = fmaf(xv, wv.w, acc4.w);
      }
      f16x4 hv = { (f16)fmaxf(acc4.x,0.f), (f16)fmaxf(acc4.y,0.f),
                   (f16)fmaxf(acc4.z,0.f), (f16)fmaxf(acc4.w,0.f) };
      *(f16x4*)&hb[e_*OCS + k0] = hv;
    }
    __syncthreads();
    // ---- chunk loop ----
    for (int c = 0; c < NCHUNK; c++){
      #pragma unroll
      for (int tt = 0; tt < 16; tt++){
        int q = c*64 + w*16 + tt;
        f32x4 acc = (f32x4){0.f,0.f,0.f,0.f};
        #pragma unroll
        for (int s=0;s<S;s++){
          f16x8 b = *(const f16x8*)(W2p + ((size_t)(q*S + s)*64 + l)*8);
          acc = __builtin_amdgcn_mfma_f32_16x16x32_f16(a[s], b, acc, 0, 0, 0);
        }
        int ocl = w*2 + (tt>>3);
        int kpos = (tt&7)*16 + (l & 15);
        f16* mp = &M[ocl*OCS + kpos];
        #pragma unroll
        for (int r=0;r<4;r++)
          mp[(size_t)(((l>>4)<<2) + r)*MNSTR] = (f16)acc[r];
      }
      __syncthreads();
      // stage 2: consume edges -> msg (LDS only; coalesced store)
      #pragma unroll
      for (int r2 = 0; r2 < ECAP/32; r2++){
        int ee = r2*32 + eslot;
        if (ee < ecnt){
          int e = ebase + ee;
          int s_ = srcs[e];
          int ln = s_ - n0;
          float acc = bt[ln*MO + c*8 + oc];
          const f16* mrow = &M[(size_t)ln*MNSTR + oc*OCS];
          const f16* hrow = &hb[ee*OCS];
          #pragma unroll 4
          for (int kk=0; kk<16; kk++){
            f16x8 h8 = *(const f16x8*)(hrow + kk*8);
            f16x4 m0 = *(const f16x4*)(mrow + kk*8);
            f16x4 m1 = *(const f16x4*)(mrow + kk*8 + 4);
            acc = dot2acc((f16x2){h8[0],h8[1]}, (f16x2){m0[0],m0[1]}, acc);
            acc = dot2acc((f16x2){h8[2],h8[3]}, (f16x2){m0[2],m0[3]}, acc);
            acc = dot2acc((f16x2){h8[4],h8[5]}, (f16x2){m1[0],m1[1]}, acc);
            acc = dot2acc((f16x2){h8[6],h8[7]}, (f16x2){m1[2],m1[3]}, acc);
          }
          msg16[(size_t)e*MO + c*8 + oc] = (f16)acc;
        }
      }
      __syncthreads();
    }
  }
}

// dst-CSR gather of conv messages: out16[n,o] = elu(prep[n,o] + sum msg[dpos[p], o])
template<int MO>
__global__ __launch_bounds__(256) void k_msg_gather(const int* __restrict__ dptr,
    const int* __restrict__ dend, const int* __restrict__ dpos,
    const f16* __restrict__ msg, const float* __restrict__ prep,
    f16* __restrict__ out16){
  int t = threadIdx.x, l = t & 63, w = t >> 6;
  int n, o;
  if (MO == 64){ n = blockIdx.x*4 + w; o = l; }
  else         { n = blockIdx.x*8 + w*2 + (l>>5); o = l & 31; }
  int st = dptr[n], en = dend[n];
  float acc = prep[(size_t)n*MO + o];
  int p = st;
  for (; p+1 < en; p += 2){
    int q0 = dpos[p], q1 = dpos[p+1];
    acc += (float)msg[(size_t)q0*MO + o];
    acc += (float)msg[(size_t)q1*MO + o];
  }
  if (p < en) acc += (float)msg[(size_t)dpos[p]*MO + o];
  out16[(size_t)n*MO + o] = (f16)elu1(acc);
}

// ---------------- pooling via cluster-CSR, dual-level ----------------
__global__ __launch_bounds__(256) void k_pool_gather_dual(const int* __restrict__ aptr,
    const int* __restrict__ aend, const int* __restrict__ ans2, const int* __restrict__ ans3,
    const f16* __restrict__ h, const float* __restrict__ iso2, const float* __restrict__ iso3,
    f16* __restrict__ h16){
  int l = threadIdx.x & 63, w = threadIdx.x >> 6;
  int cg = blockIdx.x*4 + w;               // [0, 2*NC2)
  int lvl = cg >= NC2;
  int c = cg - lvl*NC2;
  const int* ans = lvl ? ans3 : ans2;
  const float* iso = lvl ? iso3 : iso2;
  int st = aptr[cg], en = aend[cg];
  float acc = 0.f;
  int e = st;
  for (; e+1 < en; e += 2){
    int n0 = ans[e], n1 = ans[e+1];
    acc += (float)h[(size_t)n0*64 + l];
    acc += (float)h[(size_t)n1*64 + l];
  }
  if (e < en) acc += (float)h[(size_t)ans[e]*64 + l];
  int cnt = en - st;
  float val = (cnt > 0) ? acc / (float)cnt : 0.f;
  h16[(size_t)cg*128 + l] = (f16)val;
  h16[(size_t)cg*128 + 64 + l] = (f16)iso[(size_t)c*64 + l];
}

// ---------------- GraphConv (dual-level) ----------------
// pack all four [Wrel|Wroot] pairs into one buffer
#define BP_O4 0
#define BP_O5 16384
#define BP_O6 24576
#define BP_O7 40960
__global__ __launch_bounds__(256) void k_packB_all(
    const float* __restrict__ W4r, const float* __restrict__ W4o,
    const float* __restrict__ W5r, const float* __restrict__ W5o,
    const float* __restrict__ W6r, const float* __restrict__ W6o,
    const float* __restrict__ W7r, const float* __restrict__ W7o,
    f16* __restrict__ Bp){
  int t = blockIdx.x*256 + threadIdx.x;
  const float *Wrel, *Wroot; int S, base;
  if      (t < BP_O5){ Wrel=W4r; Wroot=W4o; S=4; base=BP_O4; }
  else if (t < BP_O6){ Wrel=W5r; Wroot=W5o; S=2; base=BP_O5; }
  else if (t < BP_O7){ Wrel=W6r; Wroot=W6o; S=4; base=BP_O6; }
  else if (t < 49152){ Wrel=W7r; Wroot=W7o; S=2; base=BP_O7; }
  else return;
  int u = t - base;
  int j = u & 7, l = (u >> 3) & 63, cs = u >> 9;
  int s = cs % S, c = cs / S;
  int k = s*32 + ((l>>4)<<3) + j;
  int n = (c<<4) + (l & 15);
  float v = (n < 64) ? Wrel[k*64 + n] : Wroot[k*64 + (n - 64)];
  Bp[t] = (f16)v;
}

template<int S>
__global__ __launch_bounds__(256) void k_gc_mfma_dual(const f16* __restrict__ Abase,
    const f16* __restrict__ Bp, int bpo2, int bpo3,
    const float* __restrict__ bias2, const float* __restrict__ bias3,
    f16* __restrict__ y16, f16* __restrict__ rbuf16){
  const int half = NC2/64;
  int lvl = blockIdx.x >= half;
  int bloc = blockIdx.x - lvl*half;
  const f16* A = Abase + (size_t)lvl*NC2*(S*32);
  const f16* B = Bp + (lvl ? bpo3 : bpo2);
  const float* bias = lvl ? bias3 : bias2;
  f16* y  = y16 + (size_t)lvl*NC2*64;
  f16* rb = rbuf16 + (size_t)lvl*NC2*64;
  int l = threadIdx.x & 63, w = threadIdx.x >> 6;
  int r0 = bloc*64 + w*16;
  const f16* arow = A + (size_t)(r0 + (l & 15))*(S*32);
  f16x8 a[S];
  #pragma unroll
  for (int s=0;s<S;s++) a[s] = *(const f16x8*)(arow + s*32 + ((l>>4)<<3));
  f32x4 acc[8];
  #pragma unroll
  for (int c=0;c<8;c++) acc[c] = (f32x4){0.f,0.f,0.f,0.f};
  #pragma unroll
  for (int c=0;c<8;c++){
    #pragma unroll
    for (int s=0;s<S;s++){
      f16x8 b = *(const f16x8*)(B + ((size_t)(c*S + s)*64 + l)*8);
      acc[c] = __builtin_amdgcn_mfma_f32_16x16x32_f16(a[s], b, acc[c], 0, 0, 0);
    }
  }
  #pragma unroll
  for (int c=0;c<8;c++){
    int col = c*16 + (l & 15);
    #pragma unroll
    for (int r=0;r<4;r++){
      int row = r0 + ((l>>4)<<2) + r;
      if (col < 64) y[(size_t)row*64 + col] = (f16)acc[c][r];
      else          rb[(size_t)row*64 + (col-64)] = (f16)(acc[c][r] + bias[col-64]);
    }
  }
}

__global__ __launch_bounds__(256) void k_gc_gather_dual(const int* __restrict__ dptrD,
    const int* __restrict__ dcurD, const int* __restrict__ dsrc2, const int* __restrict__ dsrc3,
    const f16* __restrict__ y16, const f16* __restrict__ rbuf16,
    f16* __restrict__ obase){
  int l = threadIdx.x & 63, w = threadIdx.x >> 6;
  int ng = blockIdx.x*4 + w;               // [0, 2*NC2)
  int lvl = ng >= NC2;
  int n = ng - lvl*NC2;
  const int* dsrc = lvl ? dsrc3 : dsrc2;
  const f16* y  = y16 + (size_t)lvl*NC2*64;
  const f16* rb = rbuf16 + (size_t)lvl*NC2*64;
  f16* o = obase + (size_t)lvl*NC2*64;
  int st = dptrD[ng], en = dcurD[ng];
  float acc = (float)rb[(size_t)n*64 + l];
  int e = st;
  for (; e+1 < en; e += 2){
    int s0 = dsrc[e], s1 = dsrc[e+1];
    acc += (float)y[(size_t)s0*64 + l];
    acc += (float)y[(size_t)s1*64 + l];
  }
  if (e < en) acc += (float)y[(size_t)dsrc[e]*64 + l];
  o[(size_t)n*64 + l] = (f16)elu1(acc);
}

// ---------------- 3-way sorted-segment batch sum ----------------
__device__ __forceinline__ int lowerb(const int* __restrict__ a, int n, int key){
  int lo = 0, hi = n;
  while (lo < hi){ int m = (lo + hi) >> 1; if (a[m] < key) lo = m + 1; else hi = m; }
  return lo;
}

__global__ __launch_bounds__(256) void k_batchsum3(const int* __restrict__ b1,
    const int* __restrict__ b2, const int* __restrict__ b3,
    const f16* __restrict__ s1, const f16* __restrict__ s2, const f16* __restrict__ s3,
    float* __restrict__ x123){
  __shared__ float red[4][64];
  int seg = blockIdx.x >> 8, b = blockIdx.x & 255;
  const int* batch = (seg==0) ? b1 : ((seg==1) ? b2 : b3);
  const f16* src   = (seg==0) ? s1 : ((seg==1) ? s2 : s3);
  int nn = (seg==0) ? NN : NC2;
  int lo = lowerb(batch, nn, b);
  int hi = lowerb(batch, nn, b+1);
  int col = threadIdx.x & 63, wq = threadIdx.x >> 6;
  float acc = 0.f;
  for (int n = lo + wq; n < hi; n += 4) acc += (float)src[(size_t)n*64 + col];
  red[wq][col] = acc;
  __syncthreads();
  if (threadIdx.x < 64){
    float s = red[0][threadIdx.x] + red[1][threadIdx.x] + red[2][threadIdx.x] + red[3][threadIdx.x];
    x123[b*192 + seg*64 + threadIdx.x] = s;
  }
}

// ---------------- FC head ----------------
__global__ __launch_bounds__(256) void k_fc1(const float* __restrict__ x123,
    const float* __restrict__ W, const float* __restrict__ b, float* __restrict__ t1){
  int t = blockIdx.x*256 + threadIdx.x;
  if (t >= NBATCH*64) return;
  int bb = t >> 6, o = t & 63;
  const float* xr = x123 + bb*192;
  float acc = b[o];
  for (int j=0;j<192;j++) acc = fmaf(xr[j], W[j*64+o] + W[(192+j)*64+o], acc);
  t1[t] = elu1(acc);
}

__global__ __launch_bounds__(256) void k_fc2(const float* __restrict__ t1,
    const float* __restrict__ W, const float* __restrict__ b, float* __restrict__ t2){
  int t = blockIdx.x*256 + threadIdx.x;
  if (t >= NBATCH*32) return;
  int bb = t >> 5, o = t & 31;
  float acc = b[o];
  for (int j=0;j<64;j++) acc = fmaf(t1[bb*64+j], W[j*32+o], acc);
  t2[t] = elu1(acc);
}

__global__ __launch_bounds__(256) void k_fc3(const float* __restrict__ t2,
    const float* __restrict__ W, const float* __restrict__ b, float* __restrict__ out){
  int t = blockIdx.x*256 + threadIdx.x;
  if (t >= NBATCH) return;
  float acc = b[0];
  for (int j=0;j<32;j++) acc = fmaf(t2[t*32+j], W[j], acc);
  out[t] = acc;
}

static inline int cdiv(long long a, int b){ return (int)((a + b - 1) / b); }

extern "C" void kernel_launch(void* const* d_in, const int* in_sizes, int n_in,
                              void* d_out, int out_size, void* d_ws, size_t ws_size,
                              hipStream_t stream) {
  const float* x0    = (const float*)d_in[0];
  const int*   ei    = (const int*)d_in[1];
  const float* ea    = (const float*)d_in[2];
  const int*   batch = (const int*)d_in[3];
  const int*   a2n   = (const int*)d_in[4];
  const int*   a2c   = (const int*)d_in[5];
  const float* iso2  = (const float*)d_in[6];
  const int*   ei2   = (const int*)d_in[7];
  const int*   b2arr = (const int*)d_in[8];
  const int*   a3n   = (const int*)d_in[9];
  const int*   a3c   = (const int*)d_in[10];
  const float* iso3  = (const float*)d_in[11];
  const int*   ei3   = (const int*)d_in[12];
  const int*   b3arr = (const int*)d_in[13];
  const float* nnp[3][6];
  for (int c=0;c<3;c++) for (int p=0;p<6;p++) nnp[c][p] = (const float*)d_in[14 + 6*c + p];
  const float* c4W[3]; const float* c5W[3]; const float* c6W[3]; const float* c7W[3];
  for (int p=0;p<3;p++){ c4W[p]=(const float*)d_in[32+p]; c5W[p]=(const float*)d_in[35+p];
                         c6W[p]=(const float*)d_in[38+p]; c7W[p]=(const float*)d_in[41+p]; }
  const float* fc1W=(const float*)d_in[44]; const float* fc1b=(const float*)d_in[45];
  const float* fc2W=(const float*)d_in[46]; const float* fc2b=(const float*)d_in[47];
  const float* fc3W=(const float*)d_in[48]; const float* fc3b=(const float*)d_in[49];
  float* outp = (float*)d_out;

  // ---- workspace carve ----
  char* ws = (char*)d_ws; size_t off = 0;
  auto alloc = [&](size_t bytes)->void*{ void* p = ws + off; off += (bytes + 255) & ~(size_t)255; return p; };
  const size_t SZ_R0 = (size_t)92*1024*1024;
  char* r0 = (char*)alloc(SZ_R0);
  // phase-1 view (NNConv): W2p 1MB | prepB 64KB | bterm 4MB | prep 4MB | msg 8MB
  f16*   W2p   = (f16*)r0;
  f16*   prepB = (f16*)(r0 + 2*1024*1024);
  float* bterm = (float*)(r0 + 2*1024*1024 + 64*1024);
  float* prep  = (float*)(r0 + 2*1024*1024 + 64*1024 + (size_t)NN*64*4);
  f16*   msg16 = (f16*)  (r0 + 2*1024*1024 + 64*1024 + (size_t)NN*64*8);
  // phase-2 view (written only after all NNConvs + gathers complete)
  size_t o2 = 0;
  auto a2 = [&](size_t bytes)->char*{ char* p = r0 + o2; o2 += (bytes + 255) & ~(size_t)255; return p; };
  f16*   h16   = (f16*)  a2((size_t)2*NC2*128*2);  // 32 MB
  f16*   y16   = (f16*)  a2((size_t)2*NC2*64*2);   // 16 MB
  f16*   rbuf16= (f16*)  a2((size_t)2*NC2*64*2);   // 16 MB
  f16*   g16   = (f16*)  a2((size_t)2*NC2*64*2);   // 16 MB
  f16*   BpGc  = (f16*)  a2((size_t)49152*2);      // 96 KB
  int*   ldegA = (int*)  a2((size_t)4*NC2*4);      // ldegA[2NC2] + ldegD[2NC2] contiguous
  int*   ldegD = ldegA + 2*NC2;
  int*   ptrA  = (int*)  a2((size_t)2*NC2*4);
  int*   curA  = (int*)  a2((size_t)2*NC2*4);
  int*   ptrD  = (int*)  a2((size_t)2*NC2*4);
  int*   curD  = (int*)  a2((size_t)2*NC2*4);
  int*   ans2  = (int*)  a2((size_t)A2N*4);
  int*   ans3  = (int*)  a2((size_t)A3N*4);
  int*   dsrc2 = (int*)  a2((size_t)ELV*4);
  int*   dsrc3 = (int*)  a2((size_t)ELV*4);
  f16*   fin2  = h16;                       // layer-2 outputs reuse h16 region
  f16*   fin3  = h16 + (size_t)NC2*64;
  // persistent
  f16*   x016  = (f16*)  alloc((size_t)NN*16*2);
  f16*   hA16  = (f16*)  alloc((size_t)NN*32*2);
  f16*   hB16  = (f16*)  alloc((size_t)NN*64*2);
  f16*   hC16  = (f16*)  alloc((size_t)NN*64*2);
  int*   deg1  = (int*)  alloc((size_t)2*NN*4);
  int*   ptr1  = (int*)  alloc((size_t)2*NN*4);
  int*   cur1  = (int*)  alloc((size_t)2*NN*4);
  int*   eids  = (int*)  alloc((size_t)E1N*4);
  int*   srcs  = (int*)  alloc((size_t)E1N*4);
  int*   dpos  = (int*)  alloc((size_t)E1N*4);
  int*   parts = (int*)  alloc((size_t)512*4);
  float* x123  = (float*)alloc((size_t)NBATCH*192*4);
  float* t1    = (float*)alloc((size_t)NBATCH*64*4);
  float* t2    = (float*)alloc((size_t)NBATCH*32*4);
  (void)ws_size; (void)n_in; (void)in_sizes; (void)out_size;

  auto scan = [&](const int* dg, int totalN, int segs, int* ptr, int* cur){
    int nb = totalN/256/segs;
    k_scan1<<<totalN/256,256,0,stream>>>(dg, ptr, parts);
    k_scan2seg<<<segs,256,0,stream>>>(parts, nb);
    k_scan3<<<totalN/256,256,0,stream>>>(parts, ptr, cur);
  };

  // ---- level-1 CSR: src-sorted edges + dst-CSR of positions (one pass) ----
  hipMemsetAsync(deg1, 0, (size_t)2*NN*4, stream);
  k_count_edge_dual<<<cdiv(E1N,256),256,0,stream>>>(ei, deg1);
  scan(deg1, 2*NN, 2, ptr1, cur1);
  k_fill_edge_dual<<<cdiv(E1N,256),256,0,stream>>>(ei, cur1, eids, srcs, dpos);
  k_cvt16<<<cdiv((long long)NN*16,256),256,0,stream>>>(x0, x016, NN*16);

  // ---- NNConv x3 (fused v5 + msg gather) ----
  auto run_nnconv = [&](const f16* xin16, int mi, int mo,
                        const float* const* P, f16* out16){
    const float* W1=P[0]; const float* b1=P[1]; const float* W2=P[2];
    const float* b2=P[3]; const float* root=P[4]; const float* bias=P[5];
    const int S = (mi > 32) ? 2 : 1;
    const int NB = (2*mo)/16;
    k_packPrep<<<cdiv((long long)NB*S*512,256),256,0,stream>>>(root, b2, prepB, mi, mo, S, NB);
    if (mi==16)      k_prep_mfma<16,1,4,32><<<NN/64,256,0,stream>>>(xin16, prepB, bias, prep, bterm);
    else if (mi==32) k_prep_mfma<32,1,8,64><<<NN/64,256,0,stream>>>(xin16, prepB, bias, prep, bterm);
    else             k_prep_mfma<64,2,8,64><<<NN/64,256,0,stream>>>(xin16, prepB, bias, prep, bterm);
    k_w2pack_full<<<cdiv((long long)mo*8*S*512,256),256,0,stream>>>(W2, W2p, mi, mo, S);
    if (mi==16)      k_nnconv_fused5<16,1,32><<<NN/16,256,0,stream>>>(xin16, W2p, ptr1, cur1, srcs, eids, ea, W1, b1, bterm, msg16);
    else if (mi==32) k_nnconv_fused5<32,1,64><<<NN/16,256,0,stream>>>(xin16, W2p, ptr1, cur1, srcs, eids, ea, W1, b1, bterm, msg16);
    else             k_nnconv_fused5<64,2,64><<<NN/16,256,0,stream>>>(xin16, W2p, ptr1, cur1, srcs, eids, ea, W1, b1, bterm, msg16);
    if (mo==32) k_msg_gather<32><<<NN/8,256,0,stream>>>(ptr1+NN, cur1+NN, dpos, msg16, prep, out16);
    else        k_msg_gather<64><<<NN/4,256,0,stream>>>(ptr1+NN, cur1+NN, dpos, msg16, prep, out16);
  };
  run_nnconv(x016, 16, 32, nnp[0], hA16);
  run_nnconv(hA16, 32, 64, nnp[1], hB16);
  run_nnconv(hB16, 64, 64, nnp[2], hC16);

  // ---- level-2/3 CSR builds (dual) ----
  hipMemsetAsync(ldegA, 0, (size_t)4*NC2*4, stream);
  k_count_assign_dual<<<cdiv((long long)(A2N+A3N),256),256,0,stream>>>(a2c, a3c, ldegA);
  scan(ldegA, 2*NC2, 2, ptrA, curA);
  k_fill_assign_dual<<<cdiv((long long)(A2N+A3N),256),256,0,stream>>>(a2n, a2c, a3n, a3c, curA, ans2, ans3);
  k_count_dst_dual<<<cdiv((long long)2*ELV,256),256,0,stream>>>(ei2, ei3, ldegD);
  scan(ldegD, 2*NC2, 2, ptrD, curD);
  k_fill_dst_dual<<<cdiv((long long)2*ELV,256),256,0,stream>>>(ei2, ei3, curD, dsrc2, dsrc3);

  // ---- levels compute (dual launches) ----
  k_pool_gather_dual<<<2*NC2/4,256,0,stream>>>(ptrA, curA, ans2, ans3, hC16, iso2, iso3, h16);
  k_packB_all<<<cdiv(49152,256),256,0,stream>>>(c4W[0], c4W[1], c5W[0], c5W[1],
                                                c6W[0], c6W[1], c7W[0], c7W[1], BpGc);
  k_gc_mfma_dual<4><<<2*NC2/64,256,0,stream>>>(h16, BpGc, BP_O4, BP_O6, c4W[2], c6W[2], y16, rbuf16);
  k_gc_gather_dual<<<2*NC2/4,256,0,stream>>>(ptrD, curD, dsrc2, dsrc3, y16, rbuf16, g16);
  k_gc_mfma_dual<2><<<2*NC2/64,256,0,stream>>>(g16, BpGc, BP_O5, BP_O7, c5W[2], c7W[2], y16, rbuf16);
  k_gc_gather_dual<<<2*NC2/4,256,0,stream>>>(ptrD, curD, dsrc2, dsrc3, y16, rbuf16, fin2);

  // ---- batch sums (3 segments in one launch) + FC head ----
  k_batchsum3<<<3*NBATCH,256,0,stream>>>(batch, b2arr, b3arr, hC16, fin2, fin3, x123);
  k_fc1<<<cdiv((long long)NBATCH*64,256),256,0,stream>>>(x123, fc1W, fc1b, t1);
  k_fc2<<<cdiv((long long)NBATCH*32,256),256,0,stream>>>(t1, fc2W, fc2b, t2);
  k_fc3<<<cdiv(NBATCH,256),256,0,stream>>>(t2, fc3W, fc3b, outp);
}